// Round 5
// baseline (76.800 us; speedup 1.0000x reference)
//
#include <hip/hip_runtime.h>
#include <math.h>

#define T_LEN   40000
#define BATCH   64
#define RESET_T 30000
#define CHUNK   32
// regime 1: steps 1..29999  -> 938 chunks (937 full, last = 15)
// regime 2: steps 30000..39999 -> 313 chunks (312 full, last = 16)
#define NC1     938
#define NFULL1  937
#define L1_LAST 15
#define NC2     313
#define L2_LAST 16
#define NC      (NC1 + NC2)
#define PI_D    3.14159265358979323846

// d_out layout in FLOATS (complex outputs validated as real part only):
// y     : (B,T,2) re-only -> B*T*2 floats at 0
// b     : (1,T)           -> T floats
// a     : (1,T)           -> T floats
// y_sum : (B,T,1) re-only -> B*T floats
#define Y_SIZE  ((size_t)BATCH * T_LEN * 2)
#define B_OFF   (Y_SIZE)
#define A_OFF   (B_OFF + T_LEN)
#define YS_OFF  (A_OFF + T_LEN)

struct Params { double alpha, beta, g0, g1, delta, k; };

__device__ __forceinline__ Params make_params(double c, double th0, double th1,
                                              double a, double b) {
    double inva = 1.0 / (1.0 + a);
    double bb   = b / (1.0 + b);
    Params p;
    p.alpha = 1.0 + c * (inva - 1.0);
    p.beta  = 1.0 + c * (inva - 1.0 + bb);
    p.g0    = c * inva * th0;
    p.g1    = c * inva * th1;
    p.delta = c * bb;
    p.k     = c * bb;
    return p;
}

__device__ __forceinline__ void get_consts(const float* tau, const float* omega,
                                           double& c, double& th0, double& th1) {
    double tv = (double)tau[0];
    c   = 0.1 / tv;
    th0 = 2.0 * PI_D * tv * (double)omega[0];
    th1 = 2.0 * PI_D * tv * (double)omega[1];
}

__device__ __forceinline__ void chunk_meta(int j, int& t0, int& len, int& regime) {
    if (j < NC1) {
        regime = 1; t0 = 1 + j * CHUNK;
        len = (j < NC1 - 1) ? CHUNK : L1_LAST;
    } else {
        int m = j - NC1;
        regime = 2; t0 = RESET_T + m * CHUNK;
        len = (m < NC2 - 1) ? CHUNK : L2_LAST;
    }
}

__device__ __forceinline__ void step(const Params& P, double& R0, double& I0,
                                     double& R1, double& I1, double z0, double z1) {
    double nR0 = P.alpha * R0 - P.g0 * I0 - P.delta * R1 + P.k * z0;
    double nI0 = P.g0 * R0 + P.beta * I0;
    double nR1 = P.alpha * R1 - P.g1 * I1 - P.delta * R0 + P.k * z1;
    double nI1 = P.g1 * R1 + P.beta * I1;
    R0 = nR0; I0 = nI0; R1 = nR1; I1 = nI1;
}

__device__ __forceinline__ void matmul4(const double* A, const double* B, double* C) {
    for (int i = 0; i < 4; ++i)
        for (int jj = 0; jj < 4; ++jj) {
            double s = 0.0;
            for (int l = 0; l < 4; ++l) s += A[i * 4 + l] * B[l * 4 + jj];
            C[i * 4 + jj] = s;
        }
}

__device__ void matpow4(const double* A, int e, double* R) {
    double base[16], tmp[16];
    for (int i = 0; i < 16; ++i) { base[i] = A[i]; R[i] = (i % 5 == 0) ? 1.0 : 0.0; }
    while (e > 0) {
        if (e & 1) { matmul4(R, base, tmp); for (int i = 0; i < 16; ++i) R[i] = tmp[i]; }
        e >>= 1;
        if (e) { matmul4(base, base, tmp); for (int i = 0; i < 16; ++i) base[i] = tmp[i]; }
    }
}

__device__ void build_A(const Params& P, double* A) {
    A[0]  = P.alpha; A[1]  = -P.g0;  A[2]  = -P.delta; A[3]  = 0.0;
    A[4]  = P.g0;    A[5]  = P.beta; A[6]  = 0.0;      A[7]  = 0.0;
    A[8]  = -P.delta;A[9]  = 0.0;    A[10] = P.alpha;  A[11] = -P.g1;
    A[12] = 0.0;     A[13] = 0.0;    A[14] = P.g1;     A[15] = P.beta;
}

// ---------------- K1: per-chunk particular solution, regime 1 only ----------------
__global__ __launch_bounds__(256) void k1_partial(const float* __restrict__ X,
        const float* tau, const float* omega, const float* a0, const float* b0,
        double* __restrict__ p_out) {
    int tid = blockIdx.x * blockDim.x + threadIdx.x;
    if (tid >= BATCH * NC1) return;
    int j = tid % NC1, b = tid / NC1;
    int t0 = 1 + j * CHUNK;
    int len = (j < NC1 - 1) ? CHUNK : L1_LAST;
    double c, th0, th1; get_consts(tau, omega, c, th0, th1);
    Params P = make_params(c, th0, th1, (double)a0[0], (double)b0[0]);
    double R0 = 0, I0 = 0, R1 = 0, I1 = 0;
    const float* xb = X + (size_t)b * T_LEN * 2 + (size_t)t0 * 2;
    if (len == CHUNK) {
        #pragma unroll 8
        for (int s = 0; s < CHUNK; ++s) {
            float2 z = *(const float2*)(xb + 2 * s);
            step(P, R0, I0, R1, I1, (double)z.x, (double)z.y);
        }
    } else {
        for (int s = 0; s < len; ++s) {
            float2 z = *(const float2*)(xb + 2 * s);
            step(P, R0, I0, R1, I1, (double)z.x, (double)z.y);
        }
    }
    double* out = p_out + ((size_t)j * BATCH + b) * 4;
    out[0] = R0; out[1] = I0; out[2] = R1; out[3] = I1;
}

// ---------------- K2: parallel chunk-level scan (Kogge-Stone), 1 block/batch ----------------
__global__ __launch_bounds__(1024) void k2_scan_par(const float* tau, const float* omega,
        const float* a0, const float* b0, const double* __restrict__ p_in,
        double* __restrict__ sstart, double* __restrict__ invn) {
    __shared__ double v[NFULL1 * 5];   // stride 5 to break LDS bank conflicts
    __shared__ double send1[4];
    int b = blockIdx.x;
    int j = threadIdx.x;

    double c, th0, th1; get_consts(tau, omega, c, th0, th1);
    Params P1 = make_params(c, th0, th1, (double)a0[0], (double)b0[0]);
    double A1[16];
    build_A(P1, A1);

    // M = M1^d, starting at d=1 where M1 = A1^CHUNK
    double M[16];
    matpow4(A1, CHUNK, M);

    if (j < NFULL1) {
        const double* p = p_in + ((size_t)j * BATCH + b) * 4;
        v[j * 5 + 0] = p[0]; v[j * 5 + 1] = p[1];
        v[j * 5 + 2] = p[2]; v[j * 5 + 3] = p[3];
    }
    __syncthreads();

    // inclusive scan: v[j] = sum_{i<=j} M1^{j-i} p_i  (full chunks 0..936)
    for (int d = 1; d <= 512; d <<= 1) {
        double n0 = 0, n1 = 0, n2 = 0, n3 = 0;
        bool act = (j < NFULL1) && (j >= d);
        if (act) {
            const double* q = &v[(j - d) * 5];
            double q0 = q[0], q1 = q[1], q2 = q[2], q3 = q[3];
            const double* w = &v[j * 5];
            n0 = M[0]  * q0 + M[1]  * q1 + M[2]  * q2 + M[3]  * q3 + w[0];
            n1 = M[4]  * q0 + M[5]  * q1 + M[6]  * q2 + M[7]  * q3 + w[1];
            n2 = M[8]  * q0 + M[9]  * q1 + M[10] * q2 + M[11] * q3 + w[2];
            n3 = M[12] * q0 + M[13] * q1 + M[14] * q2 + M[15] * q3 + w[3];
        }
        __syncthreads();
        if (act) { v[j*5+0] = n0; v[j*5+1] = n1; v[j*5+2] = n2; v[j*5+3] = n3; }
        __syncthreads();
        double tmp[16]; matmul4(M, M, tmp);
        for (int i = 0; i < 16; ++i) M[i] = tmp[i];
    }

    // regime-1 chunk start states: sstart[0]=0, sstart[j]=v[j-1]
    if (j <= NFULL1) {
        double s0 = 0, s1 = 0, s2 = 0, s3 = 0;
        if (j > 0) {
            s0 = v[(j-1)*5+0]; s1 = v[(j-1)*5+1];
            s2 = v[(j-1)*5+2]; s3 = v[(j-1)*5+3];
        }
        double* so = sstart + ((size_t)j * BATCH + b) * 4;
        so[0] = s0; so[1] = s1; so[2] = s2; so[3] = s3;
    }

    if (j == 0) {
        // end of regime 1: s_end1 = A1^L1_LAST * v[936] + p[937]
        double ML[16]; matpow4(A1, L1_LAST, ML);
        const double* q = &v[(NFULL1 - 1) * 5];
        const double* p = p_in + ((size_t)(NC1 - 1) * BATCH + b) * 4;
        double e[4];
        for (int i = 0; i < 4; ++i)
            e[i] = ML[i*4+0]*q[0] + ML[i*4+1]*q[1] + ML[i*4+2]*q[2] + ML[i*4+3]*q[3] + p[i];
        send1[0] = e[0]; send1[1] = e[1]; send1[2] = e[2]; send1[3] = e[3];
        if (b == 0) {
            // regime-2 step is y' = (1 + j*c*theta) y; y[0,RESET_T,0] = lambda0 * (e0 + j e1)
            double ct0 = c * th0;
            double yr = e[0] - ct0 * e[1];
            double yi = ct0 * e[0] + e[1];
            invn[0] = 1.0 / sqrt(yr * yr + yi * yi);
        }
    }
    __syncthreads();

    // regime-2 chunk starts, closed form: lambda_i^(CHUNK*m) applied to s_end1
    if (j < NC2) {
        double ct0 = c * th0, ct1 = c * th1;
        double n = (double)(j * CHUNK);
        double m0 = exp(0.5 * log1p(ct0 * ct0) * n), a0r = atan(ct0) * n;
        double m1 = exp(0.5 * log1p(ct1 * ct1) * n), a1r = atan(ct1) * n;
        double c0 = m0 * cos(a0r), s0 = m0 * sin(a0r);
        double c1 = m1 * cos(a1r), s1 = m1 * sin(a1r);
        double e0 = send1[0], e1 = send1[1], e2 = send1[2], e3 = send1[3];
        double* so = sstart + ((size_t)(NC1 + j) * BATCH + b) * 4;
        so[0] = c0 * e0 - s0 * e1;
        so[1] = s0 * e0 + c0 * e1;
        so[2] = c1 * e2 - s1 * e3;
        so[3] = s1 * e2 + c1 * e3;
    }
}

// ---------------- K3: replay chunks, write NORMALIZED Re(y) + fused y_sum ----------------
__global__ __launch_bounds__(256) void k3_replay(const float* __restrict__ X,
        const float* tau, const float* omega, const float* a0, const float* b0,
        const double* __restrict__ sstart, const double* __restrict__ invn,
        float* __restrict__ y_out, float* __restrict__ ysum_out) {
    int tid = blockIdx.x * blockDim.x + threadIdx.x;
    if (tid >= BATCH * NC) return;
    int j = tid % NC, b = tid / NC;
    int t0, len, regime; chunk_meta(j, t0, len, regime);
    double c, th0, th1; get_consts(tau, omega, c, th0, th1);
    Params P = (regime == 1) ? make_params(c, th0, th1, (double)a0[0], (double)b0[0])
                             : make_params(c, th0, th1, 0.0, 0.0);
    const double* sp = sstart + ((size_t)j * BATCH + b) * 4;
    double R0 = sp[0], I0 = sp[1], R1 = sp[2], I1 = sp[3];
    double inv = invn[0];
    float* yb = y_out + (size_t)b * T_LEN * 2;
    float* sb = ysum_out + (size_t)b * T_LEN;
    if (j == 0) {
        *(float2*)yb = make_float2(0.f, 0.f);  // y[:,0,:] = 0
        sb[0] = 0.f;                           // ysum[0] = 0 (stored zero)
        sb[1] = 0.f;                           // ysum[1] = sum(y[0]) = 0
    }
    const float* xb = X + (size_t)b * T_LEN * 2 + (size_t)t0 * 2;
    if (regime == 1) {
        if (len == CHUNK) {
            #pragma unroll 8
            for (int s = 0; s < CHUNK; ++s) {
                int t = t0 + s;
                float2 z = *(const float2*)(xb + 2 * s);
                step(P, R0, I0, R1, I1, (double)z.x, (double)z.y);
                *(float2*)(yb + (size_t)t * 2) =
                    make_float2((float)(R0 * inv), (float)(R1 * inv));
                sb[t + 1] = (float)((R0 + R1) * inv);
            }
        } else {
            for (int s = 0; s < len; ++s) {
                int t = t0 + s;
                float2 z = *(const float2*)(xb + 2 * s);
                step(P, R0, I0, R1, I1, (double)z.x, (double)z.y);
                *(float2*)(yb + (size_t)t * 2) =
                    make_float2((float)(R0 * inv), (float)(R1 * inv));
                sb[t + 1] = (float)((R0 + R1) * inv);
            }
        }
    } else {
        for (int s = 0; s < len; ++s) {
            int t = t0 + s;
            step(P, R0, I0, R1, I1, 0.0, 0.0);
            *(float2*)(yb + (size_t)t * 2) =
                make_float2((float)(R0 * inv), (float)(R1 * inv));
            if (t + 1 < T_LEN) sb[t + 1] = (float)((R0 + R1) * inv);
        }
    }
}

// ---------------- b / a outputs ----------------
__global__ __launch_bounds__(256) void k_ba(const float* a0, const float* b0,
        float* __restrict__ b_out, float* __restrict__ a_out) {
    int t = blockIdx.x * blockDim.x + threadIdx.x;
    if (t >= T_LEN) return;
    float bv = (t < RESET_T) ? b0[0] : 0.0f;
    float av = (t < RESET_T) ? a0[0] : 0.0f;
    b_out[t] = bv;
    a_out[t] = av;
}

extern "C" void kernel_launch(void* const* d_in, const int* in_sizes, int n_in,
                              void* d_out, int out_size, void* d_ws, size_t ws_size,
                              hipStream_t stream) {
    const float* X     = (const float*)d_in[0];
    const float* tau   = (const float*)d_in[1];
    const float* omega = (const float*)d_in[2];
    const float* a0    = (const float*)d_in[3];
    const float* b0    = (const float*)d_in[4];
    float* out = (float*)d_out;

    // Scratch in d_ws (ws_size observed = 256 MiB from harness poison fills;
    // we use < 5 MB). Fully rewritten every call: k1 writes all of p_ws,
    // k2 writes all of s_ws + invn.
    double* p_ws = (double*)d_ws;
    double* s_ws = p_ws + (size_t)NC1 * BATCH * 4;
    double* invn = s_ws + (size_t)NC * BATCH * 4;

    int n1 = BATCH * NC1;
    k1_partial<<<(n1 + 255) / 256, 256, 0, stream>>>(X, tau, omega, a0, b0, p_ws);
    k2_scan_par<<<BATCH, 1024, 0, stream>>>(tau, omega, a0, b0, p_ws, s_ws, invn);
    int n3 = BATCH * NC;
    k3_replay<<<(n3 + 255) / 256, 256, 0, stream>>>(X, tau, omega, a0, b0, s_ws, invn,
                                                    out, out + YS_OFF);
    k_ba<<<(T_LEN + 255) / 256, 256, 0, stream>>>(a0, b0, out + B_OFF, out + A_OFF);
}

// Round 6
// 66.631 us; speedup vs baseline: 1.1526x; 1.1526x over previous
//
#include <hip/hip_runtime.h>
#include <math.h>

#define T_LEN   40000
#define BATCH   64
#define RESET_T 30000
#define CHUNK   64
// regime 1: steps 1..29999  -> 469 chunks (468 full, last = 47)
// regime 2: steps 30000..39999 -> 157 chunks (156 full, last = 16)
#define NC1     469
#define NFULL1  468
#define L1_LAST 47
#define NC2     157
#define L2_LAST 16
#define NC      (NC1 + NC2)
#define PI_D    3.14159265358979323846

// d_out layout in FLOATS (complex outputs validated as real part only):
// y     : (B,T,2) re-only -> B*T*2 floats at 0
// b     : (1,T)           -> T floats
// a     : (1,T)           -> T floats
// y_sum : (B,T,1) re-only -> B*T floats
#define Y_SIZE  ((size_t)BATCH * T_LEN * 2)
#define B_OFF   (Y_SIZE)
#define A_OFF   (B_OFF + T_LEN)
#define YS_OFF  (A_OFF + T_LEN)

struct Params { double alpha, beta, g0, g1, delta, k; };

__device__ __forceinline__ Params make_params(double c, double th0, double th1,
                                              double a, double b) {
    double inva = 1.0 / (1.0 + a);
    double bb   = b / (1.0 + b);
    Params p;
    p.alpha = 1.0 + c * (inva - 1.0);
    p.beta  = 1.0 + c * (inva - 1.0 + bb);
    p.g0    = c * inva * th0;
    p.g1    = c * inva * th1;
    p.delta = c * bb;
    p.k     = c * bb;
    return p;
}

__device__ __forceinline__ void get_consts(const float* tau, const float* omega,
                                           double& c, double& th0, double& th1) {
    double tv = (double)tau[0];
    c   = 0.1 / tv;
    th0 = 2.0 * PI_D * tv * (double)omega[0];
    th1 = 2.0 * PI_D * tv * (double)omega[1];
}

__device__ __forceinline__ void chunk_meta(int j, int& t0, int& len, int& regime) {
    if (j < NC1) {
        regime = 1; t0 = 1 + j * CHUNK;
        len = (j < NC1 - 1) ? CHUNK : L1_LAST;
    } else {
        int m = j - NC1;
        regime = 2; t0 = RESET_T + m * CHUNK;
        len = (m < NC2 - 1) ? CHUNK : L2_LAST;
    }
}

__device__ __forceinline__ void step(const Params& P, double& R0, double& I0,
                                     double& R1, double& I1, double z0, double z1) {
    double nR0 = P.alpha * R0 - P.g0 * I0 - P.delta * R1 + P.k * z0;
    double nI0 = P.g0 * R0 + P.beta * I0;
    double nR1 = P.alpha * R1 - P.g1 * I1 - P.delta * R0 + P.k * z1;
    double nI1 = P.g1 * R1 + P.beta * I1;
    R0 = nR0; I0 = nI0; R1 = nR1; I1 = nI1;
}

__device__ __forceinline__ void matmul4(const double* A, const double* B, double* C) {
    for (int i = 0; i < 4; ++i)
        for (int jj = 0; jj < 4; ++jj) {
            double s = 0.0;
            for (int l = 0; l < 4; ++l) s += A[i * 4 + l] * B[l * 4 + jj];
            C[i * 4 + jj] = s;
        }
}

__device__ void matpow4(const double* A, int e, double* R) {
    double base[16], tmp[16];
    for (int i = 0; i < 16; ++i) { base[i] = A[i]; R[i] = (i % 5 == 0) ? 1.0 : 0.0; }
    while (e > 0) {
        if (e & 1) { matmul4(R, base, tmp); for (int i = 0; i < 16; ++i) R[i] = tmp[i]; }
        e >>= 1;
        if (e) { matmul4(base, base, tmp); for (int i = 0; i < 16; ++i) base[i] = tmp[i]; }
    }
}

__device__ void build_A(const Params& P, double* A) {
    A[0]  = P.alpha; A[1]  = -P.g0;  A[2]  = -P.delta; A[3]  = 0.0;
    A[4]  = P.g0;    A[5]  = P.beta; A[6]  = 0.0;      A[7]  = 0.0;
    A[8]  = -P.delta;A[9]  = 0.0;    A[10] = P.alpha;  A[11] = -P.g1;
    A[12] = 0.0;     A[13] = 0.0;    A[14] = P.g1;     A[15] = P.beta;
}

// ---------------- K1: per-chunk particular solution (regime 1) + b/a fill ----------------
__global__ __launch_bounds__(256) void k1_partial(const float* __restrict__ X,
        const float* tau, const float* omega, const float* a0, const float* b0,
        double* __restrict__ p_out, float* __restrict__ b_out, float* __restrict__ a_out) {
    int tid = blockIdx.x * blockDim.x + threadIdx.x;
    // fused b/a outputs (independent of everything else)
    if (tid < T_LEN) {
        b_out[tid] = (tid < RESET_T) ? b0[0] : 0.0f;
        a_out[tid] = (tid < RESET_T) ? a0[0] : 0.0f;
    }
    if (tid >= BATCH * NC1) return;
    int j = tid % NC1, b = tid / NC1;
    int t0 = 1 + j * CHUNK;
    int len = (j < NC1 - 1) ? CHUNK : L1_LAST;
    double c, th0, th1; get_consts(tau, omega, c, th0, th1);
    Params P = make_params(c, th0, th1, (double)a0[0], (double)b0[0]);
    double R0 = 0, I0 = 0, R1 = 0, I1 = 0;
    const float* xb = X + (size_t)b * T_LEN * 2 + (size_t)t0 * 2;
    if (len == CHUNK) {
        #pragma unroll 8
        for (int s = 0; s < CHUNK; ++s) {
            float2 z = *(const float2*)(xb + 2 * s);
            step(P, R0, I0, R1, I1, (double)z.x, (double)z.y);
        }
    } else {
        for (int s = 0; s < len; ++s) {
            float2 z = *(const float2*)(xb + 2 * s);
            step(P, R0, I0, R1, I1, (double)z.x, (double)z.y);
        }
    }
    double* out = p_out + ((size_t)j * BATCH + b) * 4;
    out[0] = R0; out[1] = I0; out[2] = R1; out[3] = I1;
}

// ---------------- K2: parallel chunk-level scan (Kogge-Stone), 1 block/batch ----------------
// All uniform heavy math (matrix powers, complex lambda powers) is precomputed
// once by thread 0 into LDS tables; scan rounds are 16 FMAs + broadcast reads.
#define NROUNDS 9   // d = 1..256 covers NFULL1=468
__global__ __launch_bounds__(512) void k2_scan_par(const float* tau, const float* omega,
        const float* a0, const float* b0, const double* __restrict__ p_in,
        double* __restrict__ sstart, double* __restrict__ invn) {
    __shared__ double v[NFULL1 * 5];        // stride 5: bank-conflict-free
    __shared__ double Mtab[NROUNDS * 16];   // M1^(2^r)
    __shared__ double LamTab[2 * 8 * 2];    // (1+j c th)^(CHUNK * 2^k), k=0..7, (re,im)
    __shared__ double send1[4];
    int b = blockIdx.x;
    int j = threadIdx.x;

    double c, th0, th1; get_consts(tau, omega, c, th0, th1);
    Params P1 = make_params(c, th0, th1, (double)a0[0], (double)b0[0]);
    double A1[16];
    build_A(P1, A1);

    if (j == 0) {
        // Mtab[0] = A1^CHUNK; Mtab[r] = Mtab[r-1]^2
        double M[16], tmp[16];
        matpow4(A1, CHUNK, M);
        for (int i = 0; i < 16; ++i) Mtab[i] = M[i];
        for (int r = 1; r < NROUNDS; ++r) {
            matmul4(&Mtab[(r-1)*16], &Mtab[(r-1)*16], tmp);
            for (int i = 0; i < 16; ++i) Mtab[r*16 + i] = tmp[i];
        }
        // LamTab: complex lambda_o = 1 + j*c*th_o ; lam^CHUNK then 7 squarings
        for (int o = 0; o < 2; ++o) {
            double ct = c * ((o == 0) ? th0 : th1);
            double lr = 1.0, li = ct;            // lam^1
            for (int k = 0; k < 6; ++k) {        // ^64 = 6 squarings
                double nr = lr*lr - li*li, ni = 2.0*lr*li; lr = nr; li = ni;
            }
            LamTab[(o*8 + 0)*2 + 0] = lr; LamTab[(o*8 + 0)*2 + 1] = li;
            for (int k = 1; k < 8; ++k) {
                double nr = lr*lr - li*li, ni = 2.0*lr*li; lr = nr; li = ni;
                LamTab[(o*8 + k)*2 + 0] = lr; LamTab[(o*8 + k)*2 + 1] = li;
            }
        }
    }

    if (j < NFULL1) {
        const double* p = p_in + ((size_t)j * BATCH + b) * 4;
        v[j * 5 + 0] = p[0]; v[j * 5 + 1] = p[1];
        v[j * 5 + 2] = p[2]; v[j * 5 + 3] = p[3];
    }
    __syncthreads();

    // inclusive scan: v[j] = sum_{i<=j} M1^{j-i} p_i  (full chunks 0..467)
    for (int r = 0, d = 1; r < NROUNDS; ++r, d <<= 1) {
        const double* M = &Mtab[r * 16];
        double n0 = 0, n1 = 0, n2 = 0, n3 = 0;
        bool act = (j < NFULL1) && (j >= d);
        if (act) {
            const double* q = &v[(j - d) * 5];
            double q0 = q[0], q1 = q[1], q2 = q[2], q3 = q[3];
            const double* w = &v[j * 5];
            n0 = M[0]  * q0 + M[1]  * q1 + M[2]  * q2 + M[3]  * q3 + w[0];
            n1 = M[4]  * q0 + M[5]  * q1 + M[6]  * q2 + M[7]  * q3 + w[1];
            n2 = M[8]  * q0 + M[9]  * q1 + M[10] * q2 + M[11] * q3 + w[2];
            n3 = M[12] * q0 + M[13] * q1 + M[14] * q2 + M[15] * q3 + w[3];
        }
        __syncthreads();
        if (act) { v[j*5+0] = n0; v[j*5+1] = n1; v[j*5+2] = n2; v[j*5+3] = n3; }
        __syncthreads();
    }

    // regime-1 chunk start states: sstart[0]=0, sstart[j]=v[j-1]
    if (j <= NFULL1) {
        double s0 = 0, s1 = 0, s2 = 0, s3 = 0;
        if (j > 0) {
            s0 = v[(j-1)*5+0]; s1 = v[(j-1)*5+1];
            s2 = v[(j-1)*5+2]; s3 = v[(j-1)*5+3];
        }
        double* so = sstart + ((size_t)j * BATCH + b) * 4;
        so[0] = s0; so[1] = s1; so[2] = s2; so[3] = s3;
    }

    if (j == 0) {
        // end of regime 1: s_end1 = A1^L1_LAST * v[467] + p[468]
        double ML[16]; matpow4(A1, L1_LAST, ML);
        const double* q = &v[(NFULL1 - 1) * 5];
        const double* p = p_in + ((size_t)(NC1 - 1) * BATCH + b) * 4;
        double e[4];
        for (int i = 0; i < 4; ++i)
            e[i] = ML[i*4+0]*q[0] + ML[i*4+1]*q[1] + ML[i*4+2]*q[2] + ML[i*4+3]*q[3] + p[i];
        send1[0] = e[0]; send1[1] = e[1]; send1[2] = e[2]; send1[3] = e[3];
        if (b == 0) {
            // y[0,RESET_T,0] = (1 + j*c*th0) * (e0 + j*e1)
            double ct0 = c * th0;
            double yr = e[0] - ct0 * e[1];
            double yi = ct0 * e[0] + e[1];
            invn[0] = 1.0 / sqrt(yr * yr + yi * yi);
        }
    }
    __syncthreads();

    // regime-2 chunk starts: sstart[NC1+m] = lam^(CHUNK*m) * s_end1 (per oscillator)
    if (j < NC2) {
        double p0r = 1.0, p0i = 0.0, p1r = 1.0, p1i = 0.0;
        int m = j;
        for (int k = 0; k < 8; ++k) {
            if (m & (1 << k)) {
                double l0r = LamTab[(0*8 + k)*2 + 0], l0i = LamTab[(0*8 + k)*2 + 1];
                double l1r = LamTab[(1*8 + k)*2 + 0], l1i = LamTab[(1*8 + k)*2 + 1];
                double t0r = p0r*l0r - p0i*l0i, t0i = p0r*l0i + p0i*l0r;
                double t1r = p1r*l1r - p1i*l1i, t1i = p1r*l1i + p1i*l1r;
                p0r = t0r; p0i = t0i; p1r = t1r; p1i = t1i;
            }
        }
        double e0 = send1[0], e1 = send1[1], e2 = send1[2], e3 = send1[3];
        double* so = sstart + ((size_t)(NC1 + j) * BATCH + b) * 4;
        so[0] = p0r * e0 - p0i * e1;
        so[1] = p0i * e0 + p0r * e1;
        so[2] = p1r * e2 - p1i * e3;
        so[3] = p1i * e2 + p1r * e3;
    }
}

// ---------------- K3: replay chunks, write NORMALIZED Re(y) + fused y_sum ----------------
__global__ __launch_bounds__(256) void k3_replay(const float* __restrict__ X,
        const float* tau, const float* omega, const float* a0, const float* b0,
        const double* __restrict__ sstart, const double* __restrict__ invn,
        float* __restrict__ y_out, float* __restrict__ ysum_out) {
    int tid = blockIdx.x * blockDim.x + threadIdx.x;
    if (tid >= BATCH * NC) return;
    int j = tid % NC, b = tid / NC;
    int t0, len, regime; chunk_meta(j, t0, len, regime);
    double c, th0, th1; get_consts(tau, omega, c, th0, th1);
    Params P = (regime == 1) ? make_params(c, th0, th1, (double)a0[0], (double)b0[0])
                             : make_params(c, th0, th1, 0.0, 0.0);
    const double* sp = sstart + ((size_t)j * BATCH + b) * 4;
    double R0 = sp[0], I0 = sp[1], R1 = sp[2], I1 = sp[3];
    double inv = invn[0];
    float* yb = y_out + (size_t)b * T_LEN * 2;
    float* sb = ysum_out + (size_t)b * T_LEN;
    if (j == 0) {
        *(float2*)yb = make_float2(0.f, 0.f);  // y[:,0,:] = 0
        sb[0] = 0.f;                           // ysum[0] = 0
        sb[1] = 0.f;                           // ysum[1] = sum(y[0]) = 0
    }
    const float* xb = X + (size_t)b * T_LEN * 2 + (size_t)t0 * 2;
    if (regime == 1) {
        if (len == CHUNK) {
            #pragma unroll 8
            for (int s = 0; s < CHUNK; ++s) {
                int t = t0 + s;
                float2 z = *(const float2*)(xb + 2 * s);
                step(P, R0, I0, R1, I1, (double)z.x, (double)z.y);
                *(float2*)(yb + (size_t)t * 2) =
                    make_float2((float)(R0 * inv), (float)(R1 * inv));
                sb[t + 1] = (float)((R0 + R1) * inv);
            }
        } else {
            for (int s = 0; s < len; ++s) {
                int t = t0 + s;
                float2 z = *(const float2*)(xb + 2 * s);
                step(P, R0, I0, R1, I1, (double)z.x, (double)z.y);
                *(float2*)(yb + (size_t)t * 2) =
                    make_float2((float)(R0 * inv), (float)(R1 * inv));
                sb[t + 1] = (float)((R0 + R1) * inv);
            }
        }
    } else {
        for (int s = 0; s < len; ++s) {
            int t = t0 + s;
            step(P, R0, I0, R1, I1, 0.0, 0.0);
            *(float2*)(yb + (size_t)t * 2) =
                make_float2((float)(R0 * inv), (float)(R1 * inv));
            if (t + 1 < T_LEN) sb[t + 1] = (float)((R0 + R1) * inv);
        }
    }
}

extern "C" void kernel_launch(void* const* d_in, const int* in_sizes, int n_in,
                              void* d_out, int out_size, void* d_ws, size_t ws_size,
                              hipStream_t stream) {
    const float* X     = (const float*)d_in[0];
    const float* tau   = (const float*)d_in[1];
    const float* omega = (const float*)d_in[2];
    const float* a0    = (const float*)d_in[3];
    const float* b0    = (const float*)d_in[4];
    float* out = (float*)d_out;

    // Scratch in d_ws (~2.3 MB of the 256 MiB workspace); fully rewritten
    // every call (k1 writes all of p_ws, k2 writes all of s_ws + invn).
    double* p_ws = (double*)d_ws;
    double* s_ws = p_ws + (size_t)NC1 * BATCH * 4;
    double* invn = s_ws + (size_t)NC * BATCH * 4;

    int n1 = BATCH * NC1;             // 30016 worker threads
    int g1 = (T_LEN + 255) / 256;     // grid covers max(n1, T_LEN) = 40000
    k1_partial<<<g1, 256, 0, stream>>>(X, tau, omega, a0, b0, p_ws,
                                       out + B_OFF, out + A_OFF);
    (void)n1;
    k2_scan_par<<<BATCH, 512, 0, stream>>>(tau, omega, a0, b0, p_ws, s_ws, invn);
    int n3 = BATCH * NC;
    k3_replay<<<(n3 + 255) / 256, 256, 0, stream>>>(X, tau, omega, a0, b0, s_ws, invn,
                                                    out, out + YS_OFF);
}

// Round 7
// 50.242 us; speedup vs baseline: 1.5286x; 1.3262x over previous
//
#include <hip/hip_runtime.h>
#include <math.h>

#define T_LEN   40000
#define BATCH   64
#define RESET_T 30000
#define SUB     16
// regime 1: steps 1..29999 -> 1875 sub-chunks of 16 (1874 full, last = 15)
// regime 2: steps 30000..39999 -> 625 sub-chunks of 16 (all full)
#define NS1     1875
#define L1_LAST 15
#define NS2     625
#define NS      (NS1 + NS2)
// scan groups: 4 subs each; groups 0..467 full (64 steps), group 468 = 3 subs (47 steps)
#define NG      469
#define NGFULL  468
#define NROUNDS 9
#define PI_D    3.14159265358979323846

// d_out layout in FLOATS (complex outputs validated as real part only):
// y     : (B,T,2) re-only -> B*T*2 floats at 0
// b     : (1,T)           -> T floats
// a     : (1,T)           -> T floats
// y_sum : (B,T,1) re-only -> B*T floats
#define Y_SIZE  ((size_t)BATCH * T_LEN * 2)
#define B_OFF   (Y_SIZE)
#define A_OFF   (B_OFF + T_LEN)
#define YS_OFF  (A_OFF + T_LEN)

struct Params { double alpha, beta, g0, g1, delta, k; };

__device__ __forceinline__ Params make_params(double c, double th0, double th1,
                                              double a, double b) {
    double inva = 1.0 / (1.0 + a);
    double bb   = b / (1.0 + b);
    Params p;
    p.alpha = 1.0 + c * (inva - 1.0);
    p.beta  = 1.0 + c * (inva - 1.0 + bb);
    p.g0    = c * inva * th0;
    p.g1    = c * inva * th1;
    p.delta = c * bb;
    p.k     = c * bb;
    return p;
}

__device__ __forceinline__ void get_consts(const float* tau, const float* omega,
                                           double& c, double& th0, double& th1) {
    double tv = (double)tau[0];
    c   = 0.1 / tv;
    th0 = 2.0 * PI_D * tv * (double)omega[0];
    th1 = 2.0 * PI_D * tv * (double)omega[1];
}

__device__ __forceinline__ void step(const Params& P, double& R0, double& I0,
                                     double& R1, double& I1, double z0, double z1) {
    double nR0 = P.alpha * R0 - P.g0 * I0 - P.delta * R1 + P.k * z0;
    double nI0 = P.g0 * R0 + P.beta * I0;
    double nR1 = P.alpha * R1 - P.g1 * I1 - P.delta * R0 + P.k * z1;
    double nI1 = P.g1 * R1 + P.beta * I1;
    R0 = nR0; I0 = nI0; R1 = nR1; I1 = nI1;
}

__device__ __forceinline__ void matmul4(const double* A, const double* B, double* C) {
    for (int i = 0; i < 4; ++i)
        for (int jj = 0; jj < 4; ++jj) {
            double s = 0.0;
            for (int l = 0; l < 4; ++l) s += A[i * 4 + l] * B[l * 4 + jj];
            C[i * 4 + jj] = s;
        }
}

__device__ void matpow4(const double* A, int e, double* R) {
    double base[16], tmp[16];
    for (int i = 0; i < 16; ++i) { base[i] = A[i]; R[i] = (i % 5 == 0) ? 1.0 : 0.0; }
    while (e > 0) {
        if (e & 1) { matmul4(R, base, tmp); for (int i = 0; i < 16; ++i) R[i] = tmp[i]; }
        e >>= 1;
        if (e) { matmul4(base, base, tmp); for (int i = 0; i < 16; ++i) base[i] = tmp[i]; }
    }
}

__device__ void build_A(const Params& P, double* A) {
    A[0]  = P.alpha; A[1]  = -P.g0;  A[2]  = -P.delta; A[3]  = 0.0;
    A[4]  = P.g0;    A[5]  = P.beta; A[6]  = 0.0;      A[7]  = 0.0;
    A[8]  = -P.delta;A[9]  = 0.0;    A[10] = P.alpha;  A[11] = -P.g1;
    A[12] = 0.0;     A[13] = 0.0;    A[14] = P.g1;     A[15] = P.beta;
}

// ---------------- K1: 16-step particular solutions (regime 1) + b/a fill ----------------
__global__ __launch_bounds__(256) void k1_partial(const float* __restrict__ X,
        const float* tau, const float* omega, const float* a0, const float* b0,
        double* __restrict__ p_out, float* __restrict__ b_out, float* __restrict__ a_out) {
    int tid = blockIdx.x * blockDim.x + threadIdx.x;
    if (tid < T_LEN) {
        b_out[tid] = (tid < RESET_T) ? b0[0] : 0.0f;
        a_out[tid] = (tid < RESET_T) ? a0[0] : 0.0f;
    }
    if (tid >= BATCH * NS1) return;
    int j = tid % NS1, b = tid / NS1;
    int t0 = 1 + j * SUB;
    int len = (j < NS1 - 1) ? SUB : L1_LAST;
    double c, th0, th1; get_consts(tau, omega, c, th0, th1);
    Params P = make_params(c, th0, th1, (double)a0[0], (double)b0[0]);
    double R0 = 0, I0 = 0, R1 = 0, I1 = 0;
    const float* xb = X + (size_t)b * T_LEN * 2 + (size_t)t0 * 2;
    if (len == SUB) {
        #pragma unroll
        for (int s = 0; s < SUB; ++s) {
            float2 z = *(const float2*)(xb + 2 * s);
            step(P, R0, I0, R1, I1, (double)z.x, (double)z.y);
        }
    } else {
        for (int s = 0; s < len; ++s) {
            float2 z = *(const float2*)(xb + 2 * s);
            step(P, R0, I0, R1, I1, (double)z.x, (double)z.y);
        }
    }
    double* out = p_out + ((size_t)j * BATCH + b) * 4;
    out[0] = R0; out[1] = I0; out[2] = R1; out[3] = I1;
}

// ---------------- K2: combine(4x16->64) + Kogge-Stone scan + expand(64->16) ----------------
__global__ __launch_bounds__(512) void k2_scan_par(const float* tau, const float* omega,
        const float* a0, const float* b0, const double* __restrict__ p_in,
        double* __restrict__ s_out, double* __restrict__ invn) {
    __shared__ double v[NGFULL * 5];        // stride 5: bank-conflict-free
    __shared__ double Mtab[NROUNDS * 16];   // (A^64)^(2^r)
    __shared__ double A16s[16], A32s[16], A48s[16], A15s[16];
    __shared__ double LamTab[2 * 10 * 2];   // lam^(16*2^k), k=0..9, per oscillator
    __shared__ double send1[4];
    int b = blockIdx.x;
    int j = threadIdx.x;

    double c, th0, th1; get_consts(tau, omega, c, th0, th1);
    Params P1 = make_params(c, th0, th1, (double)a0[0], (double)b0[0]);
    double A1[16];
    build_A(P1, A1);

    if (j == 0) {
        double t2[16], t4[16], t8[16], tmp[16];
        matmul4(A1, A1, t2); matmul4(t2, t2, t4); matmul4(t4, t4, t8);
        matmul4(t8, t8, A16s);                  // A^16
        matmul4(A16s, A16s, A32s);              // A^32
        matmul4(A16s, A32s, A48s);              // A^48
        matmul4(A32s, A32s, &Mtab[0]);          // A^64
        for (int r = 1; r < NROUNDS; ++r) {
            matmul4(&Mtab[(r-1)*16], &Mtab[(r-1)*16], tmp);
            for (int i = 0; i < 16; ++i) Mtab[r*16 + i] = tmp[i];
        }
        matpow4(A1, L1_LAST, A15s);             // A^15 (last sub of regime 1)
        for (int o = 0; o < 2; ++o) {
            double ct = c * ((o == 0) ? th0 : th1);
            double lr = 1.0, li = ct;           // lam^1
            for (int k = 0; k < 4; ++k) {       // ^16 = 4 squarings
                double nr = lr*lr - li*li, ni = 2.0*lr*li; lr = nr; li = ni;
            }
            LamTab[(o*10 + 0)*2 + 0] = lr; LamTab[(o*10 + 0)*2 + 1] = li;
            for (int k = 1; k < 10; ++k) {
                double nr = lr*lr - li*li, ni = 2.0*lr*li; lr = nr; li = ni;
                LamTab[(o*10 + k)*2 + 0] = lr; LamTab[(o*10 + k)*2 + 1] = li;
            }
        }
    }

    // per-thread loads of the 4 sub-partials of group j (kept for expansion)
    double p0[4], p1[4], p2[4], p3[4];
    if (j < NGFULL) {
        const double* p = p_in + ((size_t)(4*j) * BATCH + b) * 4;
        for (int i = 0; i < 4; ++i) p0[i] = p[i];
        p += (size_t)BATCH * 4; for (int i = 0; i < 4; ++i) p1[i] = p[i];
        p += (size_t)BATCH * 4; for (int i = 0; i < 4; ++i) p2[i] = p[i];
        p += (size_t)BATCH * 4; for (int i = 0; i < 4; ++i) p3[i] = p[i];
    } else if (j == NGFULL) {  // subs 1872..1874 only
        const double* p = p_in + ((size_t)(4*j) * BATCH + b) * 4;
        for (int i = 0; i < 4; ++i) p0[i] = p[i];
        p += (size_t)BATCH * 4; for (int i = 0; i < 4; ++i) p1[i] = p[i];
        p += (size_t)BATCH * 4; for (int i = 0; i < 4; ++i) p2[i] = p[i];
    }
    __syncthreads();

    // combine: group particular pg = A48 p0 + A32 p1 + A16 p2 + p3
    if (j < NGFULL) {
        for (int i = 0; i < 4; ++i) {
            double s = p3[i];
            for (int l = 0; l < 4; ++l)
                s += A48s[i*4+l]*p0[l] + A32s[i*4+l]*p1[l] + A16s[i*4+l]*p2[l];
            v[j*5 + i] = s;
        }
    }
    __syncthreads();

    // inclusive Kogge-Stone over full groups 0..467
    for (int r = 0, d = 1; r < NROUNDS; ++r, d <<= 1) {
        const double* M = &Mtab[r * 16];
        double n0 = 0, n1 = 0, n2 = 0, n3 = 0;
        bool act = (j < NGFULL) && (j >= d);
        if (act) {
            const double* q = &v[(j - d) * 5];
            double q0 = q[0], q1 = q[1], q2 = q[2], q3 = q[3];
            const double* w = &v[j * 5];
            n0 = M[0]  * q0 + M[1]  * q1 + M[2]  * q2 + M[3]  * q3 + w[0];
            n1 = M[4]  * q0 + M[5]  * q1 + M[6]  * q2 + M[7]  * q3 + w[1];
            n2 = M[8]  * q0 + M[9]  * q1 + M[10] * q2 + M[11] * q3 + w[2];
            n3 = M[12] * q0 + M[13] * q1 + M[14] * q2 + M[15] * q3 + w[3];
        }
        __syncthreads();
        if (act) { v[j*5+0] = n0; v[j*5+1] = n1; v[j*5+2] = n2; v[j*5+3] = n3; }
        __syncthreads();
    }

    // expand: group start -> 16-granularity sub starts (s = A16*s + p_sub)
    if (j <= NGFULL) {
        double s[4] = {0, 0, 0, 0};
        if (j > 0) { s[0]=v[(j-1)*5+0]; s[1]=v[(j-1)*5+1]; s[2]=v[(j-1)*5+2]; s[3]=v[(j-1)*5+3]; }
        int sub0 = 4 * j;
        int nsub = (j < NGFULL) ? 4 : 3;
        const double* psub[3] = { p0, p1, p2 };
        for (int k = 0; k < nsub; ++k) {
            double* so = s_out + ((size_t)(sub0 + k) * BATCH + b) * 4;
            so[0]=s[0]; so[1]=s[1]; so[2]=s[2]; so[3]=s[3];
            if (k < 3) {  // advance with A16 (not needed past last write for full groups)
                double ns[4];
                for (int i = 0; i < 4; ++i)
                    ns[i] = A16s[i*4+0]*s[0] + A16s[i*4+1]*s[1]
                          + A16s[i*4+2]*s[2] + A16s[i*4+3]*s[3] + psub[k][i];
                s[0]=ns[0]; s[1]=ns[1]; s[2]=ns[2]; s[3]=ns[3];
            }
        }
        if (j == NGFULL) {
            // s currently = A16*s16[1874] + p2 -- WRONG hop for 15-step sub; redo with A15:
            // recompute from the stored start of sub 1874:
            const double* so = s_out + ((size_t)(sub0 + 2) * BATCH + b) * 4;
            double e[4];
            for (int i = 0; i < 4; ++i)
                e[i] = A15s[i*4+0]*so[0] + A15s[i*4+1]*so[1]
                     + A15s[i*4+2]*so[2] + A15s[i*4+3]*so[3] + p2[i];
            send1[0]=e[0]; send1[1]=e[1]; send1[2]=e[2]; send1[3]=e[3];
            if (b == 0) {
                double ct0 = c * th0;   // y[0,RESET_T,0] = (1 + j*c*th0)*(e0 + j*e1)
                double yr = e[0] - ct0 * e[1];
                double yi = ct0 * e[0] + e[1];
                invn[0] = 1.0 / sqrt(yr * yr + yi * yi);
            }
        }
    }
    __syncthreads();

    // regime-2 sub starts: lam^(16m) * s_end1, m = 0..624
    for (int m = j; m < NS2; m += 512) {
        double q0r = 1.0, q0i = 0.0, q1r = 1.0, q1i = 0.0;
        for (int k = 0; k < 10; ++k) {
            if (m & (1 << k)) {
                double l0r = LamTab[(0*10+k)*2+0], l0i = LamTab[(0*10+k)*2+1];
                double l1r = LamTab[(1*10+k)*2+0], l1i = LamTab[(1*10+k)*2+1];
                double t0r = q0r*l0r - q0i*l0i, t0i = q0r*l0i + q0i*l0r;
                double t1r = q1r*l1r - q1i*l1i, t1i = q1r*l1i + q1i*l1r;
                q0r=t0r; q0i=t0i; q1r=t1r; q1i=t1i;
            }
        }
        double e0 = send1[0], e1 = send1[1], e2 = send1[2], e3 = send1[3];
        double* so = s_out + ((size_t)(NS1 + m) * BATCH + b) * 4;
        so[0] = q0r * e0 - q0i * e1;
        so[1] = q0i * e0 + q0r * e1;
        so[2] = q1r * e2 - q1i * e3;
        so[3] = q1i * e2 + q1r * e3;
    }
}

// ---------------- K3: 16-step replay, write NORMALIZED Re(y) + fused y_sum ----------------
__global__ __launch_bounds__(256) void k3_replay(const float* __restrict__ X,
        const float* tau, const float* omega, const float* a0, const float* b0,
        const double* __restrict__ s_in, const double* __restrict__ invn,
        float* __restrict__ y_out, float* __restrict__ ysum_out) {
    int tid = blockIdx.x * blockDim.x + threadIdx.x;
    if (tid >= BATCH * NS) return;
    int j = tid % NS, b = tid / NS;
    double c, th0, th1; get_consts(tau, omega, c, th0, th1);
    const double* sp = s_in + ((size_t)j * BATCH + b) * 4;
    double R0 = sp[0], I0 = sp[1], R1 = sp[2], I1 = sp[3];
    double inv = invn[0];
    float* yb = y_out + (size_t)b * T_LEN * 2;
    float* sb = ysum_out + (size_t)b * T_LEN;
    if (j == 0) {
        *(float2*)yb = make_float2(0.f, 0.f);  // y[:,0,:] = 0
        sb[0] = 0.f;                           // ysum[0] = 0
        sb[1] = 0.f;                           // ysum[1] = sum(y[0]) = 0
    }
    if (j < NS1) {
        Params P = make_params(c, th0, th1, (double)a0[0], (double)b0[0]);
        int t0 = 1 + j * SUB;
        int len = (j < NS1 - 1) ? SUB : L1_LAST;
        const float* xb = X + (size_t)b * T_LEN * 2 + (size_t)t0 * 2;
        if (len == SUB) {
            #pragma unroll
            for (int s = 0; s < SUB; ++s) {
                int t = t0 + s;
                float2 z = *(const float2*)(xb + 2 * s);
                step(P, R0, I0, R1, I1, (double)z.x, (double)z.y);
                *(float2*)(yb + (size_t)t * 2) =
                    make_float2((float)(R0 * inv), (float)(R1 * inv));
                sb[t + 1] = (float)((R0 + R1) * inv);
            }
        } else {
            for (int s = 0; s < len; ++s) {
                int t = t0 + s;
                float2 z = *(const float2*)(xb + 2 * s);
                step(P, R0, I0, R1, I1, (double)z.x, (double)z.y);
                *(float2*)(yb + (size_t)t * 2) =
                    make_float2((float)(R0 * inv), (float)(R1 * inv));
                sb[t + 1] = (float)((R0 + R1) * inv);
            }
        }
    } else {
        Params P = make_params(c, th0, th1, 0.0, 0.0);
        int m = j - NS1;
        int t0 = RESET_T + m * SUB;
        #pragma unroll
        for (int s = 0; s < SUB; ++s) {
            int t = t0 + s;
            step(P, R0, I0, R1, I1, 0.0, 0.0);
            *(float2*)(yb + (size_t)t * 2) =
                make_float2((float)(R0 * inv), (float)(R1 * inv));
            if (t + 1 < T_LEN) sb[t + 1] = (float)((R0 + R1) * inv);
        }
    }
}

extern "C" void kernel_launch(void* const* d_in, const int* in_sizes, int n_in,
                              void* d_out, int out_size, void* d_ws, size_t ws_size,
                              hipStream_t stream) {
    const float* X     = (const float*)d_in[0];
    const float* tau   = (const float*)d_in[1];
    const float* omega = (const float*)d_in[2];
    const float* a0    = (const float*)d_in[3];
    const float* b0    = (const float*)d_in[4];
    float* out = (float*)d_out;

    // Scratch in d_ws (~9 MB of 256 MiB); fully rewritten every call.
    double* p_ws = (double*)d_ws;                        // NS1*BATCH*4 doubles
    double* s_ws = p_ws + (size_t)NS1 * BATCH * 4;       // NS*BATCH*4 doubles
    double* invn = s_ws + (size_t)NS * BATCH * 4;

    int n1 = BATCH * NS1;   // 120,000 (also covers T_LEN=40,000 b/a fill)
    k1_partial<<<(n1 + 255) / 256, 256, 0, stream>>>(X, tau, omega, a0, b0, p_ws,
                                                     out + B_OFF, out + A_OFF);
    k2_scan_par<<<BATCH, 512, 0, stream>>>(tau, omega, a0, b0, p_ws, s_ws, invn);
    int n3 = BATCH * NS;    // 160,000
    k3_replay<<<(n3 + 255) / 256, 256, 0, stream>>>(X, tau, omega, a0, b0, s_ws, invn,
                                                    out, out + YS_OFF);
}

// Round 8
// 45.835 us; speedup vs baseline: 1.6756x; 1.0961x over previous
//
#include <hip/hip_runtime.h>
#include <math.h>

#define T_LEN   40000
#define BATCH   64
#define RESET_T 30000
#define SUB     16
// regime 1: steps 1..29999 -> 1875 sub-chunks of 16 (1874 full, last = 15)
// regime 2: steps 30000..39999 -> 625 sub-chunks of 16 (all full)
#define NS1     1875
#define L1_LAST 15
#define NS2     625
#define NS      (NS1 + NS2)
// scan groups: 4 subs each; groups 0..467 full (64 steps), group 468 = 3 subs (47 steps)
#define NG      469
#define NGFULL  468
#define NROUNDS 9
#define PI_D    3.14159265358979323846

// d_out layout in FLOATS (complex outputs validated as real part only):
// y     : (B,T,2) re-only -> B*T*2 floats at 0
// b     : (1,T)           -> T floats
// a     : (1,T)           -> T floats
// y_sum : (B,T,1) re-only -> B*T floats
#define Y_SIZE  ((size_t)BATCH * T_LEN * 2)
#define B_OFF   (Y_SIZE)
#define A_OFF   (B_OFF + T_LEN)
#define YS_OFF  (A_OFF + T_LEN)

struct Params { double alpha, beta, g0, g1, delta, k; };

__device__ __forceinline__ Params make_params(double c, double th0, double th1,
                                              double a, double b) {
    double inva = 1.0 / (1.0 + a);
    double bb   = b / (1.0 + b);
    Params p;
    p.alpha = 1.0 + c * (inva - 1.0);
    p.beta  = 1.0 + c * (inva - 1.0 + bb);
    p.g0    = c * inva * th0;
    p.g1    = c * inva * th1;
    p.delta = c * bb;
    p.k     = c * bb;
    return p;
}

__device__ __forceinline__ void get_consts(const float* tau, const float* omega,
                                           double& c, double& th0, double& th1) {
    double tv = (double)tau[0];
    c   = 0.1 / tv;
    th0 = 2.0 * PI_D * tv * (double)omega[0];
    th1 = 2.0 * PI_D * tv * (double)omega[1];
}

__device__ __forceinline__ void step(const Params& P, double& R0, double& I0,
                                     double& R1, double& I1, double z0, double z1) {
    double nR0 = P.alpha * R0 - P.g0 * I0 - P.delta * R1 + P.k * z0;
    double nI0 = P.g0 * R0 + P.beta * I0;
    double nR1 = P.alpha * R1 - P.g1 * I1 - P.delta * R0 + P.k * z1;
    double nI1 = P.g1 * R1 + P.beta * I1;
    R0 = nR0; I0 = nI0; R1 = nR1; I1 = nI1;
}

__device__ __forceinline__ void matmul4(const double* A, const double* B, double* C) {
    for (int i = 0; i < 4; ++i)
        for (int jj = 0; jj < 4; ++jj) {
            double s = 0.0;
            for (int l = 0; l < 4; ++l) s += A[i * 4 + l] * B[l * 4 + jj];
            C[i * 4 + jj] = s;
        }
}

__device__ void matpow4(const double* A, int e, double* R) {
    double base[16], tmp[16];
    for (int i = 0; i < 16; ++i) { base[i] = A[i]; R[i] = (i % 5 == 0) ? 1.0 : 0.0; }
    while (e > 0) {
        if (e & 1) { matmul4(R, base, tmp); for (int i = 0; i < 16; ++i) R[i] = tmp[i]; }
        e >>= 1;
        if (e) { matmul4(base, base, tmp); for (int i = 0; i < 16; ++i) base[i] = tmp[i]; }
    }
}

__device__ void build_A(const Params& P, double* A) {
    A[0]  = P.alpha; A[1]  = -P.g0;  A[2]  = -P.delta; A[3]  = 0.0;
    A[4]  = P.g0;    A[5]  = P.beta; A[6]  = 0.0;      A[7]  = 0.0;
    A[8]  = -P.delta;A[9]  = 0.0;    A[10] = P.alpha;  A[11] = -P.g1;
    A[12] = 0.0;     A[13] = 0.0;    A[14] = P.g1;     A[15] = P.beta;
}

// ---------------- K1: 16-step particular solutions (regime 1) + b/a fill ----------------
// p_out layout: [b][j] -> p_out[(b*NS1 + j)*4 + i]  (coalesced: addr == tid*32B)
__global__ __launch_bounds__(256) void k1_partial(const float* __restrict__ X,
        const float* tau, const float* omega, const float* a0, const float* b0,
        double* __restrict__ p_out, float* __restrict__ b_out, float* __restrict__ a_out) {
    int tid = blockIdx.x * blockDim.x + threadIdx.x;
    if (tid < T_LEN) {
        b_out[tid] = (tid < RESET_T) ? b0[0] : 0.0f;
        a_out[tid] = (tid < RESET_T) ? a0[0] : 0.0f;
    }
    if (tid >= BATCH * NS1) return;
    int j = tid % NS1, b = tid / NS1;
    int t0 = 1 + j * SUB;
    int len = (j < NS1 - 1) ? SUB : L1_LAST;
    double c, th0, th1; get_consts(tau, omega, c, th0, th1);
    Params P = make_params(c, th0, th1, (double)a0[0], (double)b0[0]);
    double R0 = 0, I0 = 0, R1 = 0, I1 = 0;
    const float* xb = X + (size_t)b * T_LEN * 2 + (size_t)t0 * 2;
    if (len == SUB) {
        #pragma unroll
        for (int s = 0; s < SUB; ++s) {
            float2 z = *(const float2*)(xb + 2 * s);
            step(P, R0, I0, R1, I1, (double)z.x, (double)z.y);
        }
    } else {
        for (int s = 0; s < len; ++s) {
            float2 z = *(const float2*)(xb + 2 * s);
            step(P, R0, I0, R1, I1, (double)z.x, (double)z.y);
        }
    }
    double* out = p_out + ((size_t)b * NS1 + j) * 4;
    out[0] = R0; out[1] = I0; out[2] = R1; out[3] = I1;
}

// ---------------- K2: combine(4x16->64) + Kogge-Stone scan + expand(64->16) ----------------
// p_in  layout [b][j4]: block b, thread j reads 128B contiguous at (b*NS1 + 4j)*4 doubles
// s_out layout [b][sub]: (b*NS + sub)*4 doubles
__global__ __launch_bounds__(512) void k2_scan_par(const float* tau, const float* omega,
        const float* a0, const float* b0, const double* __restrict__ p_in,
        double* __restrict__ s_out, double* __restrict__ invn) {
    __shared__ double v[NGFULL * 5];        // stride 5: bank-conflict-free
    __shared__ double Mtab[NROUNDS * 16];   // (A^64)^(2^r)
    __shared__ double A16s[16], A32s[16], A48s[16], A15s[16];
    __shared__ double LamTab[2 * 10 * 2];   // lam^(16*2^k), k=0..9, per oscillator
    __shared__ double send1[4];
    int b = blockIdx.x;
    int j = threadIdx.x;

    double c, th0, th1; get_consts(tau, omega, c, th0, th1);
    Params P1 = make_params(c, th0, th1, (double)a0[0], (double)b0[0]);
    double A1[16];
    build_A(P1, A1);

    if (j == 0) {
        double t2[16], t4[16], t8[16], tmp[16];
        matmul4(A1, A1, t2); matmul4(t2, t2, t4); matmul4(t4, t4, t8);
        matmul4(t8, t8, A16s);                  // A^16
        matmul4(A16s, A16s, A32s);              // A^32
        matmul4(A16s, A32s, A48s);              // A^48
        matmul4(A32s, A32s, &Mtab[0]);          // A^64
        for (int r = 1; r < NROUNDS; ++r) {
            matmul4(&Mtab[(r-1)*16], &Mtab[(r-1)*16], tmp);
            for (int i = 0; i < 16; ++i) Mtab[r*16 + i] = tmp[i];
        }
        matpow4(A1, L1_LAST, A15s);             // A^15 (last sub of regime 1)
        for (int o = 0; o < 2; ++o) {
            double ct = c * ((o == 0) ? th0 : th1);
            double lr = 1.0, li = ct;           // lam^1
            for (int k = 0; k < 4; ++k) {       // ^16 = 4 squarings
                double nr = lr*lr - li*li, ni = 2.0*lr*li; lr = nr; li = ni;
            }
            LamTab[(o*10 + 0)*2 + 0] = lr; LamTab[(o*10 + 0)*2 + 1] = li;
            for (int k = 1; k < 10; ++k) {
                double nr = lr*lr - li*li, ni = 2.0*lr*li; lr = nr; li = ni;
                LamTab[(o*10 + k)*2 + 0] = lr; LamTab[(o*10 + k)*2 + 1] = li;
            }
        }
    }

    // per-thread loads of the 4 sub-partials of group j (kept for expansion)
    double p0[4], p1[4], p2[4], p3[4];
    if (j < NGFULL) {
        const double* p = p_in + ((size_t)b * NS1 + 4*j) * 4;
        for (int i = 0; i < 4; ++i) p0[i] = p[i];
        for (int i = 0; i < 4; ++i) p1[i] = p[4 + i];
        for (int i = 0; i < 4; ++i) p2[i] = p[8 + i];
        for (int i = 0; i < 4; ++i) p3[i] = p[12 + i];
    } else if (j == NGFULL) {  // subs 1872..1874 only
        const double* p = p_in + ((size_t)b * NS1 + 4*j) * 4;
        for (int i = 0; i < 4; ++i) p0[i] = p[i];
        for (int i = 0; i < 4; ++i) p1[i] = p[4 + i];
        for (int i = 0; i < 4; ++i) p2[i] = p[8 + i];
    }
    __syncthreads();

    // combine: group particular pg = A48 p0 + A32 p1 + A16 p2 + p3
    if (j < NGFULL) {
        for (int i = 0; i < 4; ++i) {
            double s = p3[i];
            for (int l = 0; l < 4; ++l)
                s += A48s[i*4+l]*p0[l] + A32s[i*4+l]*p1[l] + A16s[i*4+l]*p2[l];
            v[j*5 + i] = s;
        }
    }
    __syncthreads();

    // inclusive Kogge-Stone over full groups 0..467
    for (int r = 0, d = 1; r < NROUNDS; ++r, d <<= 1) {
        const double* M = &Mtab[r * 16];
        double n0 = 0, n1 = 0, n2 = 0, n3 = 0;
        bool act = (j < NGFULL) && (j >= d);
        if (act) {
            const double* q = &v[(j - d) * 5];
            double q0 = q[0], q1 = q[1], q2 = q[2], q3 = q[3];
            const double* w = &v[j * 5];
            n0 = M[0]  * q0 + M[1]  * q1 + M[2]  * q2 + M[3]  * q3 + w[0];
            n1 = M[4]  * q0 + M[5]  * q1 + M[6]  * q2 + M[7]  * q3 + w[1];
            n2 = M[8]  * q0 + M[9]  * q1 + M[10] * q2 + M[11] * q3 + w[2];
            n3 = M[12] * q0 + M[13] * q1 + M[14] * q2 + M[15] * q3 + w[3];
        }
        __syncthreads();
        if (act) { v[j*5+0] = n0; v[j*5+1] = n1; v[j*5+2] = n2; v[j*5+3] = n3; }
        __syncthreads();
    }

    // expand: group start -> 16-granularity sub starts (s = A16*s + p_sub)
    if (j <= NGFULL) {
        double s[4] = {0, 0, 0, 0};
        if (j > 0) { s[0]=v[(j-1)*5+0]; s[1]=v[(j-1)*5+1]; s[2]=v[(j-1)*5+2]; s[3]=v[(j-1)*5+3]; }
        int sub0 = 4 * j;
        int nsub = (j < NGFULL) ? 4 : 3;
        const double* psub[3] = { p0, p1, p2 };
        for (int k = 0; k < nsub; ++k) {
            double* so = s_out + ((size_t)b * NS + (sub0 + k)) * 4;
            so[0]=s[0]; so[1]=s[1]; so[2]=s[2]; so[3]=s[3];
            if (k < 3) {
                double ns[4];
                for (int i = 0; i < 4; ++i)
                    ns[i] = A16s[i*4+0]*s[0] + A16s[i*4+1]*s[1]
                          + A16s[i*4+2]*s[2] + A16s[i*4+3]*s[3] + psub[k][i];
                s[0]=ns[0]; s[1]=ns[1]; s[2]=ns[2]; s[3]=ns[3];
            }
        }
        if (j == NGFULL) {
            // end of regime 1: advance the stored start of sub 1874 by A^15 + p2
            const double* so = s_out + ((size_t)b * NS + (sub0 + 2)) * 4;
            double e[4];
            for (int i = 0; i < 4; ++i)
                e[i] = A15s[i*4+0]*so[0] + A15s[i*4+1]*so[1]
                     + A15s[i*4+2]*so[2] + A15s[i*4+3]*so[3] + p2[i];
            send1[0]=e[0]; send1[1]=e[1]; send1[2]=e[2]; send1[3]=e[3];
            if (b == 0) {
                double ct0 = c * th0;   // y[0,RESET_T,0] = (1 + j*c*th0)*(e0 + j*e1)
                double yr = e[0] - ct0 * e[1];
                double yi = ct0 * e[0] + e[1];
                invn[0] = 1.0 / sqrt(yr * yr + yi * yi);
            }
        }
    }
    __syncthreads();

    // regime-2 sub starts: lam^(16m) * s_end1, m = 0..624
    for (int m = j; m < NS2; m += 512) {
        double q0r = 1.0, q0i = 0.0, q1r = 1.0, q1i = 0.0;
        for (int k = 0; k < 10; ++k) {
            if (m & (1 << k)) {
                double l0r = LamTab[(0*10+k)*2+0], l0i = LamTab[(0*10+k)*2+1];
                double l1r = LamTab[(1*10+k)*2+0], l1i = LamTab[(1*10+k)*2+1];
                double t0r = q0r*l0r - q0i*l0i, t0i = q0r*l0i + q0i*l0r;
                double t1r = q1r*l1r - q1i*l1i, t1i = q1r*l1i + q1i*l1r;
                q0r=t0r; q0i=t0i; q1r=t1r; q1i=t1i;
            }
        }
        double e0 = send1[0], e1 = send1[1], e2 = send1[2], e3 = send1[3];
        double* so = s_out + ((size_t)b * NS + (NS1 + m)) * 4;
        so[0] = q0r * e0 - q0i * e1;
        so[1] = q0i * e0 + q0r * e1;
        so[2] = q1r * e2 - q1i * e3;
        so[3] = q1i * e2 + q1r * e3;
    }
}

// ---------------- K3: 16-step replay, write NORMALIZED Re(y) + fused y_sum ----------------
// s_in layout [b][j]: addr == tid*32B -> coalesced
__global__ __launch_bounds__(256) void k3_replay(const float* __restrict__ X,
        const float* tau, const float* omega, const float* a0, const float* b0,
        const double* __restrict__ s_in, const double* __restrict__ invn,
        float* __restrict__ y_out, float* __restrict__ ysum_out) {
    int tid = blockIdx.x * blockDim.x + threadIdx.x;
    if (tid >= BATCH * NS) return;
    int j = tid % NS, b = tid / NS;
    double c, th0, th1; get_consts(tau, omega, c, th0, th1);
    const double* sp = s_in + ((size_t)b * NS + j) * 4;
    double R0 = sp[0], I0 = sp[1], R1 = sp[2], I1 = sp[3];
    double inv = invn[0];
    float* yb = y_out + (size_t)b * T_LEN * 2;
    float* sb = ysum_out + (size_t)b * T_LEN;
    if (j == 0) {
        *(float2*)yb = make_float2(0.f, 0.f);  // y[:,0,:] = 0
        sb[0] = 0.f;                           // ysum[0] = 0
        sb[1] = 0.f;                           // ysum[1] = sum(y[0]) = 0
    }
    if (j < NS1) {
        Params P = make_params(c, th0, th1, (double)a0[0], (double)b0[0]);
        int t0 = 1 + j * SUB;
        int len = (j < NS1 - 1) ? SUB : L1_LAST;
        const float* xb = X + (size_t)b * T_LEN * 2 + (size_t)t0 * 2;
        if (len == SUB) {
            #pragma unroll
            for (int s = 0; s < SUB; ++s) {
                int t = t0 + s;
                float2 z = *(const float2*)(xb + 2 * s);
                step(P, R0, I0, R1, I1, (double)z.x, (double)z.y);
                *(float2*)(yb + (size_t)t * 2) =
                    make_float2((float)(R0 * inv), (float)(R1 * inv));
                sb[t + 1] = (float)((R0 + R1) * inv);
            }
        } else {
            for (int s = 0; s < len; ++s) {
                int t = t0 + s;
                float2 z = *(const float2*)(xb + 2 * s);
                step(P, R0, I0, R1, I1, (double)z.x, (double)z.y);
                *(float2*)(yb + (size_t)t * 2) =
                    make_float2((float)(R0 * inv), (float)(R1 * inv));
                sb[t + 1] = (float)((R0 + R1) * inv);
            }
        }
    } else {
        Params P = make_params(c, th0, th1, 0.0, 0.0);
        int m = j - NS1;
        int t0 = RESET_T + m * SUB;
        #pragma unroll
        for (int s = 0; s < SUB; ++s) {
            int t = t0 + s;
            step(P, R0, I0, R1, I1, 0.0, 0.0);
            *(float2*)(yb + (size_t)t * 2) =
                make_float2((float)(R0 * inv), (float)(R1 * inv));
            if (t + 1 < T_LEN) sb[t + 1] = (float)((R0 + R1) * inv);
        }
    }
}

extern "C" void kernel_launch(void* const* d_in, const int* in_sizes, int n_in,
                              void* d_out, int out_size, void* d_ws, size_t ws_size,
                              hipStream_t stream) {
    const float* X     = (const float*)d_in[0];
    const float* tau   = (const float*)d_in[1];
    const float* omega = (const float*)d_in[2];
    const float* a0    = (const float*)d_in[3];
    const float* b0    = (const float*)d_in[4];
    float* out = (float*)d_out;

    // Scratch in d_ws (~9 MB of 256 MiB); fully rewritten every call.
    double* p_ws = (double*)d_ws;                        // [BATCH][NS1][4]
    double* s_ws = p_ws + (size_t)NS1 * BATCH * 4;       // [BATCH][NS][4]
    double* invn = s_ws + (size_t)NS * BATCH * 4;

    int n1 = BATCH * NS1;   // 120,000 (also covers T_LEN=40,000 b/a fill)
    k1_partial<<<(n1 + 255) / 256, 256, 0, stream>>>(X, tau, omega, a0, b0, p_ws,
                                                     out + B_OFF, out + A_OFF);
    k2_scan_par<<<BATCH, 512, 0, stream>>>(tau, omega, a0, b0, p_ws, s_ws, invn);
    int n3 = BATCH * NS;    // 160,000
    k3_replay<<<(n3 + 255) / 256, 256, 0, stream>>>(X, tau, omega, a0, b0, s_ws, invn,
                                                    out, out + YS_OFF);
}